// Round 1
// baseline (3196.120 us; speedup 1.0000x reference)
//
#include <hip/hip_runtime.h>

#define NB 16          // batch
#define NLEN 1024      // nodes
#define DD 128         // feature dim
#define BN (NB*NLEN)
#define BND ((size_t)NB*NLEN*DD)
#define BNN ((size_t)NB*NLEN*NLEN)

// ---------------------------------------------------------------- embed: h = x @ Ew^T
__global__ __launch_bounds__(256)
void k_embed(const float* __restrict__ x, const float* __restrict__ Ew, float* __restrict__ h) {
    __shared__ float rows[8][DD];
    int g = blockIdx.x * 8;
    int tid = threadIdx.x;
    {
        int nl = tid >> 5, c4 = (tid & 31) * 4;
        *(float4*)&rows[nl][c4] = *(const float4*)&x[(size_t)(g + nl) * DD + c4];
    }
    __syncthreads();
    int t = tid & 127, half = tid >> 7;
    const float* wr = Ew + (size_t)t * DD;
    float acc[4] = {0.f, 0.f, 0.f, 0.f};
    for (int k = 0; k < DD; k++) {
        float w = wr[k];
#pragma unroll
        for (int m = 0; m < 4; m++) acc[m] += rows[half + 2 * m][k] * w;
    }
#pragma unroll
    for (int m = 0; m < 4; m++) h[(size_t)(g + half + 2 * m) * DD + t] = acc[m];
}

// ------------------------------------------------- proj: hbr = h@W^T + b ; hA = hbr@A
__global__ __launch_bounds__(256)
void k_proj(const float* __restrict__ h, const float* __restrict__ W,
            const float* __restrict__ bias, const float* __restrict__ A,
            float* __restrict__ hbr, float* __restrict__ hA) {
    __shared__ float rows[8][DD];
    __shared__ float brows[8][DD];
    int g = blockIdx.x * 8;
    int tid = threadIdx.x;
    {
        int nl = tid >> 5, c4 = (tid & 31) * 4;
        *(float4*)&rows[nl][c4] = *(const float4*)&h[(size_t)(g + nl) * DD + c4];
    }
    __syncthreads();
    int t = tid & 127, half = tid >> 7;
    {
        const float* wr = W + (size_t)t * DD;
        float bv = bias[t];
        float acc[4];
#pragma unroll
        for (int m = 0; m < 4; m++) acc[m] = bv;
        for (int k = 0; k < DD; k++) {
            float w = wr[k];
#pragma unroll
            for (int m = 0; m < 4; m++) acc[m] += rows[half + 2 * m][k] * w;
        }
#pragma unroll
        for (int m = 0; m < 4; m++) {
            brows[half + 2 * m][t] = acc[m];
            hbr[(size_t)(g + half + 2 * m) * DD + t] = acc[m];
        }
    }
    __syncthreads();
    {
        float acc[4] = {0.f, 0.f, 0.f, 0.f};
        for (int d = 0; d < DD; d++) {
            float a = A[(size_t)d * DD + t];
#pragma unroll
            for (int m = 0; m < 4; m++) acc[m] += brows[half + 2 * m][d] * a;
        }
#pragma unroll
        for (int m = 0; m < 4; m++) hA[(size_t)(g + half + 2 * m) * DD + t] = acc[m];
    }
}

// ------------------------------------------------- e[b,i,j] = sum_l hA[b,i,l]*hbr[b,j,l]  (NT)
#define LDE 68
__global__ __launch_bounds__(256)
void k_egemm(const float* __restrict__ hAg, const float* __restrict__ hbg,
             float* __restrict__ e) {
    __shared__ float At[64 * LDE];
    __shared__ float Bt[64 * LDE];
    int b = blockIdx.z;
    int i0 = blockIdx.y * 64, j0 = blockIdx.x * 64;
    const float* Ag = hAg + (size_t)b * NLEN * DD + (size_t)i0 * DD;
    const float* Bg = hbg + (size_t)b * NLEN * DD + (size_t)j0 * DD;
    int tid = threadIdx.x;
    int tx = tid & 15, ty = tid >> 4;
    float acc[4][4] = {};
    for (int k0 = 0; k0 < DD; k0 += 64) {
#pragma unroll
        for (int v = 0; v < 4; v++) {
            int idx = v * 256 + tid;
            int r = idx >> 4, c4 = (idx & 15) * 4;
            *(float4*)&At[r * LDE + c4] = *(const float4*)&Ag[(size_t)r * DD + k0 + c4];
            *(float4*)&Bt[r * LDE + c4] = *(const float4*)&Bg[(size_t)r * DD + k0 + c4];
        }
        __syncthreads();
        for (int k = 0; k < 64; k += 4) {
            float4 a4[4], b4[4];
#pragma unroll
            for (int i = 0; i < 4; i++) a4[i] = *(const float4*)&At[(ty + 16 * i) * LDE + k];
#pragma unroll
            for (int j = 0; j < 4; j++) b4[j] = *(const float4*)&Bt[(tx + 16 * j) * LDE + k];
#pragma unroll
            for (int i = 0; i < 4; i++) {
                const float* ap = &a4[i].x;
#pragma unroll
                for (int j = 0; j < 4; j++) {
                    const float* bp = &b4[j].x;
                    acc[i][j] += ap[0] * bp[0] + ap[1] * bp[1] + ap[2] * bp[2] + ap[3] * bp[3];
                }
            }
        }
        __syncthreads();
    }
    float* eg = e + (size_t)b * NLEN * NLEN;
#pragma unroll
    for (int i = 0; i < 4; i++) {
        size_t rbase = (size_t)(i0 + ty + 16 * i) * NLEN + j0 + tx;
#pragma unroll
        for (int j = 0; j < 4; j++) eg[rbase + 16 * j] = acc[i][j];
    }
}

// --------------------------- em = adj>0 ? (e + e^T) : 0   (tile-pair, in place, symmetric)
__global__ __launch_bounds__(256)
void k_symmask(const float* __restrict__ adj, float* __restrict__ e) {
    int b = blockIdx.z, ti = blockIdx.y, tj = blockIdx.x;
    if (ti > tj) return;
    __shared__ float T1[64 * 65];
    __shared__ float T2[64 * 65];
    float* E = e + (size_t)b * NLEN * NLEN;
    const float* Adj = adj + (size_t)b * NLEN * NLEN;
    int tid = threadIdx.x;
#pragma unroll
    for (int v = 0; v < 16; v++) {
        int idx = v * 256 + tid;
        int r = idx >> 6, c = idx & 63;
        T1[r * 65 + c] = E[(size_t)(ti * 64 + r) * NLEN + tj * 64 + c];
        T2[r * 65 + c] = E[(size_t)(tj * 64 + r) * NLEN + ti * 64 + c];
    }
    __syncthreads();
#pragma unroll
    for (int v = 0; v < 16; v++) {
        int idx = v * 256 + tid;
        int r = idx >> 6, c = idx & 63;
        float s = T1[r * 65 + c] + T2[c * 65 + r];
        float a = Adj[(size_t)(ti * 64 + r) * NLEN + tj * 64 + c];
        float em = (a > 0.f) ? s : 0.f;
        E[(size_t)(ti * 64 + r) * NLEN + tj * 64 + c] = em;
        T1[r * 65 + c] = em;
    }
    if (ti == tj) return;
    __syncthreads();
#pragma unroll
    for (int v = 0; v < 16; v++) {
        int idx = v * 256 + tid;
        int r = idx >> 6, c = idx & 63;
        E[(size_t)(tj * 64 + r) * NLEN + ti * 64 + c] = T1[c * 65 + r];
    }
}

// ---------------- per-column softmax stats (em symmetric -> use rows, coalesced)
__global__ __launch_bounds__(256)
void k_stats(const float* __restrict__ e, float* __restrict__ mOut, float* __restrict__ rsOut) {
    int bj = blockIdx.x;
    const float* row = e + (size_t)bj * NLEN;
    float4 v = *(const float4*)&row[threadIdx.x * 4];
    float mx = fmaxf(fmaxf(v.x, v.y), fmaxf(v.z, v.w));
    for (int off = 32; off; off >>= 1) mx = fmaxf(mx, __shfl_down(mx, off));
    __shared__ float red[4];
    __shared__ float Msh;
    int lane = threadIdx.x & 63, wv = threadIdx.x >> 6;
    if (lane == 0) red[wv] = mx;
    __syncthreads();
    if (threadIdx.x == 0) Msh = fmaxf(fmaxf(red[0], red[1]), fmaxf(red[2], red[3]));
    __syncthreads();
    float M = Msh;
    float s = __expf(v.x - M) + __expf(v.y - M) + __expf(v.z - M) + __expf(v.w - M);
    for (int off = 32; off; off >>= 1) s += __shfl_down(s, off);
    if (lane == 0) red[wv] = s;
    __syncthreads();
    if (threadIdx.x == 0) {
        mOut[bj] = M;
        rsOut[bj] = 1.f / (red[0] + red[1] + red[2] + red[3]);
    }
}

// ---------------- att[b,i,j] = adj * exp(em - m[j]) * rs[j]   (in place)
__global__ __launch_bounds__(256)
void k_attapply(const float* __restrict__ adj, const float* __restrict__ mIn,
                const float* __restrict__ rsIn, float* __restrict__ e) {
    size_t i4 = ((size_t)blockIdx.x * 256 + threadIdx.x) * 4;
    size_t rowi = i4 >> 10;            // b*N + i
    int j0 = (int)(i4 & 1023);
    int b = (int)(rowi >> 10);
    float4 ev = *(const float4*)&e[i4];
    float4 av = *(const float4*)&adj[i4];
    float4 mv = *(const float4*)&mIn[b * NLEN + j0];
    float4 rv = *(const float4*)&rsIn[b * NLEN + j0];
    float4 o;
    o.x = av.x * (__expf(ev.x - mv.x) * rv.x);
    o.y = av.y * (__expf(ev.y - mv.y) * rv.y);
    o.z = av.z * (__expf(ev.z - mv.z) * rv.z);
    o.w = av.w * (__expf(ev.w - mv.w) * rv.w);
    *(float4*)&e[i4] = o;
}

// ---------------- az/z-update GEMM: C = att @ zin ; mode0: relu ; mode1: coeff*hbr+(1-c)*relu
#define LDA 68
#define LDB 132
__global__ __launch_bounds__(256)
void k_azgemm(const float* __restrict__ att, const float* __restrict__ zin,
              const float* __restrict__ hbr, const float* __restrict__ coeff,
              float* __restrict__ out, int mode) {
    __shared__ float At[32 * LDA];
    __shared__ float Bt[64 * LDB];
    int b = blockIdx.z;
    int i0 = blockIdx.x * 32;
    const float* Ag = att + (size_t)b * NLEN * NLEN + (size_t)i0 * NLEN;
    const float* Bg = zin + (size_t)b * NLEN * DD;
    int tid = threadIdx.x;
    int tx = tid & 15, ty = tid >> 4;
    float4 acc[2][2] = {};
    for (int k0 = 0; k0 < NLEN; k0 += 64) {
#pragma unroll
        for (int v = 0; v < 2; v++) {
            int idx = v * 256 + tid;
            int r = idx >> 4, c4 = (idx & 15) * 4;
            *(float4*)&At[r * LDA + c4] = *(const float4*)&Ag[(size_t)r * NLEN + k0 + c4];
        }
#pragma unroll
        for (int v = 0; v < 8; v++) {
            int idx = v * 256 + tid;
            int r = idx >> 5, c4 = (idx & 31) * 4;
            *(float4*)&Bt[r * LDB + c4] = *(const float4*)&Bg[(size_t)(k0 + r) * DD + c4];
        }
        __syncthreads();
        for (int kk = 0; kk < 64; kk += 4) {
            float4 a40 = *(const float4*)&At[ty * LDA + kk];
            float4 a41 = *(const float4*)&At[(ty + 16) * LDA + kk];
            const float* a0p = &a40.x;
            const float* a1p = &a41.x;
#pragma unroll
            for (int dk = 0; dk < 4; dk++) {
                float a0 = a0p[dk], a1 = a1p[dk];
                float4 b0 = *(const float4*)&Bt[(kk + dk) * LDB + 4 * tx];
                float4 b1 = *(const float4*)&Bt[(kk + dk) * LDB + 64 + 4 * tx];
                acc[0][0].x += a0 * b0.x; acc[0][0].y += a0 * b0.y; acc[0][0].z += a0 * b0.z; acc[0][0].w += a0 * b0.w;
                acc[0][1].x += a0 * b1.x; acc[0][1].y += a0 * b1.y; acc[0][1].z += a0 * b1.z; acc[0][1].w += a0 * b1.w;
                acc[1][0].x += a1 * b0.x; acc[1][0].y += a1 * b0.y; acc[1][0].z += a1 * b0.z; acc[1][0].w += a1 * b0.w;
                acc[1][1].x += a1 * b1.x; acc[1][1].y += a1 * b1.y; acc[1][1].z += a1 * b1.z; acc[1][1].w += a1 * b1.w;
            }
        }
        __syncthreads();
    }
    float* og = out + (size_t)b * NLEN * DD;
    const float* hg = hbr + (size_t)b * NLEN * DD;
#pragma unroll
    for (int i = 0; i < 2; i++) {
        int r = i0 + ty + 16 * i;
        float cf = (mode == 1) ? coeff[b * NLEN + r] : 0.f;
#pragma unroll
        for (int jj = 0; jj < 2; jj++) {
            float4 v = acc[i][jj];
            v.x = fmaxf(v.x, 0.f); v.y = fmaxf(v.y, 0.f);
            v.z = fmaxf(v.z, 0.f); v.w = fmaxf(v.w, 0.f);
            if (mode == 1) {
                float4 hv = *(const float4*)&hg[(size_t)r * DD + jj * 64 + 4 * tx];
                v.x = cf * hv.x + (1.f - cf) * v.x;
                v.y = cf * hv.y + (1.f - cf) * v.y;
                v.z = cf * hv.z + (1.f - cf) * v.z;
                v.w = cf * hv.w + (1.f - cf) * v.w;
            }
            *(float4*)&og[(size_t)r * DD + jj * 64 + 4 * tx] = v;
        }
    }
}

// ---------------- gate coefficient: sigmoid([hbr, az] . gw + gb)
__global__ __launch_bounds__(256)
void k_coeff(const float* __restrict__ hbr, const float* __restrict__ az,
             const float* __restrict__ gw, const float* __restrict__ gb,
             float* __restrict__ cf) {
    int node = blockIdx.x * 4 + (threadIdx.x >> 6);
    int l = threadIdx.x & 63;
    const float* hp = hbr + (size_t)node * DD;
    const float* ap = az + (size_t)node * DD;
    float acc = hp[l] * gw[l] + hp[l + 64] * gw[l + 64] + ap[l] * gw[128 + l] + ap[l + 64] * gw[192 + l];
    for (int off = 32; off; off >>= 1) acc += __shfl_down(acc, off);
    if (l == 0) cf[node] = 1.f / (1.f + __expf(-(acc + gb[0])));
}

// ---------------- hop-1 elementwise z = c*hbr + (1-c)*az  (az already relu'd)
__global__ __launch_bounds__(256)
void k_zupd(const float* __restrict__ hbr, const float* __restrict__ az,
            const float* __restrict__ cf, float* __restrict__ z) {
    size_t i4 = ((size_t)blockIdx.x * 256 + threadIdx.x) * 4;
    int node = (int)(i4 >> 7);
    float c = cf[node];
    float4 hv = *(const float4*)&hbr[i4];
    float4 av = *(const float4*)&az[i4];
    float4 o;
    o.x = c * hv.x + (1.f - c) * av.x;
    o.y = c * hv.y + (1.f - c) * av.y;
    o.z = c * hv.z + (1.f - c) * av.z;
    o.w = c * hv.w + (1.f - c) * av.w;
    *(float4*)&z[i4] = o;
}

// ---------------- h = z2 - z1
__global__ __launch_bounds__(256)
void k_sub(const float* __restrict__ a2, const float* __restrict__ a1, float* __restrict__ o) {
    size_t i4 = ((size_t)blockIdx.x * 256 + threadIdx.x) * 4;
    float4 v2 = *(const float4*)&a2[i4];
    float4 v1 = *(const float4*)&a1[i4];
    float4 r;
    r.x = v2.x - v1.x; r.y = v2.y - v1.y; r.z = v2.z - v1.z; r.w = v2.w - v1.w;
    *(float4*)&o[i4] = r;
}

// ---------------- masked mean-pool + 4-layer MLP head
__global__ __launch_bounds__(128)
void k_final(const float* __restrict__ h, const float* __restrict__ valid,
             const float* __restrict__ w0, const float* __restrict__ b0,
             const float* __restrict__ w1, const float* __restrict__ b1,
             const float* __restrict__ w2, const float* __restrict__ b2,
             const float* __restrict__ w3, const float* __restrict__ b3,
             float* __restrict__ out) {
    int b = blockIdx.x, t = threadIdx.x;
    __shared__ float y0[DD], y1[DD];
    __shared__ float sred[2];
    float vs = 0.f;
    for (int n = t; n < NLEN; n += 128) vs += valid[b * NLEN + n];
    for (int off = 32; off; off >>= 1) vs += __shfl_down(vs, off);
    if ((t & 63) == 0) sred[t >> 6] = vs;
    __syncthreads();
    float vsum = sred[0] + sred[1];
    const float* hb = h + (size_t)b * NLEN * DD;
    float acc = 0.f;
    for (int n = 0; n < NLEN; n++) acc += hb[(size_t)n * DD + t] * valid[b * NLEN + n];
    y0[t] = acc / vsum;
    __syncthreads();
    float a = b0[t];
    for (int k = 0; k < DD; k++) a += y0[k] * w0[t * DD + k];
    y1[t] = fmaxf(a, 0.f);
    __syncthreads();
    a = b1[t];
    for (int k = 0; k < DD; k++) a += y1[k] * w1[t * DD + k];
    y0[t] = fmaxf(a, 0.f);
    __syncthreads();
    a = b2[t];
    for (int k = 0; k < DD; k++) a += y0[k] * w2[t * DD + k];
    y1[t] = fmaxf(a, 0.f);
    __syncthreads();
    float p = y1[t] * w3[t];
    for (int off = 32; off; off >>= 1) p += __shfl_down(p, off);
    if ((t & 63) == 0) sred[t >> 6] = p;
    __syncthreads();
    if (t == 0) out[b] = 1.f / (1.f + __expf(-(sred[0] + sred[1] + b3[0])));
}

extern "C" void kernel_launch(void* const* d_in, const int* in_sizes, int n_in,
                              void* d_out, int out_size, void* d_ws, size_t ws_size,
                              hipStream_t stream) {
    (void)in_sizes; (void)n_in; (void)out_size; (void)ws_size;
    const float* x     = (const float*)d_in[0];
    const float* adj1  = (const float*)d_in[1];
    const float* adj2  = (const float*)d_in[2];
    const float* valid = (const float*)d_in[3];
    const float* Ew    = (const float*)d_in[4];
    const float* gW    = (const float*)d_in[5];
    const float* gb    = (const float*)d_in[6];
    const float* gA    = (const float*)d_in[7];
    const float* gatew = (const float*)d_in[8];
    const float* gateb = (const float*)d_in[9];
    const float* w0 = (const float*)d_in[10]; const float* b0 = (const float*)d_in[11];
    const float* w1 = (const float*)d_in[12]; const float* b1 = (const float*)d_in[13];
    const float* w2 = (const float*)d_in[14]; const float* b2 = (const float*)d_in[15];
    const float* w3 = (const float*)d_in[16]; const float* b3 = (const float*)d_in[17];
    float* out = (float*)d_out;

    // workspace carve (~137 MB): 9 node buffers + att + stats
    float* p = (float*)d_ws;
    float* h    = p; p += BND;
    float* hbr1 = p; p += BND;
    float* hbr2 = p; p += BND;
    float* hAb  = p; p += BND;
    float* azg  = p; p += BND;
    float* z1a  = p; p += BND;
    float* z1b  = p; p += BND;
    float* z2a  = p; p += BND;
    float* z2b  = p; p += BND;
    float* att  = p; p += BNN;
    float* cfb  = p; p += BN;
    float* mb   = p; p += BN;
    float* rsb  = p; p += BN;

    k_embed<<<2048, 256, 0, stream>>>(x, Ew, h);
    const int NH[4] = {1, 2, 3, 4};
    float* zfin[2] = {nullptr, nullptr};
    for (int k = 0; k < 4; k++) {
        for (int br = 0; br < 2; br++) {
            const float* adj = br ? adj2 : adj1;
            float* hbr = br ? hbr2 : hbr1;
            float* za  = br ? z2a : z1a;
            float* zb  = br ? z2b : z1b;
            k_proj<<<2048, 256, 0, stream>>>(h, gW + (size_t)k * DD * DD, gb + (size_t)k * DD,
                                             gA + (size_t)k * DD * DD, hbr, hAb);
            k_egemm<<<dim3(16, 16, NB), 256, 0, stream>>>(hAb, hbr, att);
            k_symmask<<<dim3(16, 16, NB), 256, 0, stream>>>(adj, att);
            k_stats<<<BN, 256, 0, stream>>>(att, mb, rsb);
            k_attapply<<<16384, 256, 0, stream>>>(adj, mb, rsb, att);
            k_azgemm<<<dim3(32, 1, NB), 256, 0, stream>>>(att, hbr, hbr, cfb, azg, 0);
            k_coeff<<<4096, 256, 0, stream>>>(hbr, azg, gatew + (size_t)k * 2 * DD, gateb + k, cfb);
            k_zupd<<<2048, 256, 0, stream>>>(hbr, azg, cfb, za);   // hop 1 reuses gate az
            float* zi = za; float* zo = zb;
            for (int hop = 1; hop < NH[k]; hop++) {
                k_azgemm<<<dim3(32, 1, NB), 256, 0, stream>>>(att, zi, hbr, cfb, zo, 1);
                float* tswap = zi; zi = zo; zo = tswap;
            }
            zfin[br] = zi;
        }
        k_sub<<<2048, 256, 0, stream>>>(zfin[1], zfin[0], h);
    }
    k_final<<<16, 128, 0, stream>>>(h, valid, w0, b0, w1, b1, w2, b2, w3, b3, out);
}

// Round 2
// 1447.271 us; speedup vs baseline: 2.2084x; 2.2084x over previous
//
#include <hip/hip_runtime.h>

typedef _Float16 half_t;
typedef _Float16 half8 __attribute__((ext_vector_type(8)));
typedef _Float16 half4v __attribute__((ext_vector_type(4)));
typedef float floatx4 __attribute__((ext_vector_type(4)));

#define MFMA(a,b,c) __builtin_amdgcn_mfma_f32_16x16x32_f16(a,b,c,0,0,0)

#define NB 16
#define NLEN 1024
#define DD 128
#define BN (NB*NLEN)
#define BND ((size_t)NB*NLEN*DD)
#define BNN ((size_t)NB*NLEN*NLEN)

// ---------------------------------------------------------------- embed: h = x @ Ew^T (fp32, once)
__global__ __launch_bounds__(256)
void k_embed(const float* __restrict__ x, const float* __restrict__ Ew, float* __restrict__ h) {
    __shared__ float rows[8][DD];
    int g = blockIdx.x * 8;
    int tid = threadIdx.x;
    {
        int nl = tid >> 5, c4 = (tid & 31) * 4;
        *(float4*)&rows[nl][c4] = *(const float4*)&x[(size_t)(g + nl) * DD + c4];
    }
    __syncthreads();
    int t = tid & 127, half = tid >> 7;
    const float* wr = Ew + (size_t)t * DD;
    float acc[4] = {0.f, 0.f, 0.f, 0.f};
    for (int k = 0; k < DD; k++) {
        float w = wr[k];
#pragma unroll
        for (int m = 0; m < 4; m++) acc[m] += rows[half + 2 * m][k] * w;
    }
#pragma unroll
    for (int m = 0; m < 4; m++) h[(size_t)(g + half + 2 * m) * DD + t] = acc[m];
}

// ---------------- adjacency -> bitmask (adj values are exactly 0/1)
__global__ __launch_bounds__(256)
void k_adjmask(const float* __restrict__ adj, unsigned int* __restrict__ mask) {
    int widx = blockIdx.x * 256 + threadIdx.x;
    const float* p = adj + (size_t)widx * 32;
    unsigned int m = 0;
#pragma unroll
    for (int i = 0; i < 32; i += 4) {
        float4 v = *(const float4*)&p[i];
        m |= (v.x > 0.f ? 1u : 0u) << i;
        m |= (v.y > 0.f ? 1u : 0u) << (i + 1);
        m |= (v.z > 0.f ? 1u : 0u) << (i + 2);
        m |= (v.w > 0.f ? 1u : 0u) << (i + 3);
    }
    mask[widx] = m;
}

// ---------------- weight casts: Wf16 = gW (row-major [n][k]); ATf16[e][d] = gA[d][e]
__global__ __launch_bounds__(256)
void k_wcast(const float* __restrict__ gW, const float* __restrict__ gA,
             half_t* __restrict__ Wf, half_t* __restrict__ ATf) {
    int i = blockIdx.x * 256 + threadIdx.x;   // 4*128*128 elements
    Wf[i] = (half_t)gW[i];
    int lrem = i & 16383;
    int d = lrem >> 7, e = lrem & 127;
    ATf[(i & ~16383) + (e << 7) + d] = (half_t)gA[i];
}

// ---------------- proj (MFMA): hbr = h@W^T + b ; hA = hbr@A ; outputs f32 + f16 copies
__global__ __launch_bounds__(256)
void k_proj(const float* __restrict__ h, const half_t* __restrict__ Wf,
            const float* __restrict__ bias, const half_t* __restrict__ ATf,
            float* __restrict__ hbr, half_t* __restrict__ hbr16, half_t* __restrict__ hA16) {
    __shared__ half_t htile[32 * 136];
    __shared__ half_t hbtile[32 * 136];
    int g = blockIdx.x * 32;
    int t = threadIdx.x;
    int w = t >> 6, l = t & 63, q = l >> 4, l15 = l & 15;
#pragma unroll
    for (int v = 0; v < 4; v++) {
        int idx = v * 256 + t; int r = idx >> 5, c4 = (idx & 31) * 4;
        float4 hv = *(const float4*)&h[((size_t)(g + r) << 7) + c4];
        half4v hh = {(half_t)hv.x, (half_t)hv.y, (half_t)hv.z, (half_t)hv.w};
        *(half4v*)&htile[r * 136 + c4] = hh;
    }
    __syncthreads();
    int rowh = (w & 1) * 16;
    int c0 = (w >> 1) * 4;
    half8 a1[4];
#pragma unroll
    for (int kc = 0; kc < 4; kc++) a1[kc] = *(const half8*)&htile[(rowh + l15) * 136 + kc * 32 + q * 8];
    floatx4 acc[4];
#pragma unroll
    for (int cc = 0; cc < 4; cc++) {
        int col = (c0 + cc) * 16 + l15;
        floatx4 a = {0.f, 0.f, 0.f, 0.f};
#pragma unroll
        for (int kc = 0; kc < 4; kc++) {
            half8 bf = *(const half8*)&Wf[((size_t)col << 7) + kc * 32 + q * 8];
            a = MFMA(a1[kc], bf, a);
        }
        float bv = bias[col];
        a.x += bv; a.y += bv; a.z += bv; a.w += bv;
        acc[cc] = a;
    }
#pragma unroll
    for (int cc = 0; cc < 4; cc++) {
        int col = (c0 + cc) * 16 + l15;
#pragma unroll
        for (int r = 0; r < 4; r++) {
            int rowl = rowh + q * 4 + r;
            float vv = acc[cc][r];
            hbr[((size_t)(g + rowl) << 7) + col] = vv;
            hbtile[rowl * 136 + col] = (half_t)vv;
        }
    }
    __syncthreads();
    half8 a2[4];
#pragma unroll
    for (int kc = 0; kc < 4; kc++) a2[kc] = *(const half8*)&hbtile[(rowh + l15) * 136 + kc * 32 + q * 8];
#pragma unroll
    for (int cc = 0; cc < 4; cc++) {
        int col = (c0 + cc) * 16 + l15;
        floatx4 a = {0.f, 0.f, 0.f, 0.f};
#pragma unroll
        for (int kc = 0; kc < 4; kc++) {
            half8 bf = *(const half8*)&ATf[((size_t)col << 7) + kc * 32 + q * 8];
            a = MFMA(a2[kc], bf, a);
        }
        acc[cc] = a;
    }
    __syncthreads();
#pragma unroll
    for (int cc = 0; cc < 4; cc++) {
        int col = (c0 + cc) * 16 + l15;
#pragma unroll
        for (int r = 0; r < 4; r++) htile[(rowh + q * 4 + r) * 136 + col] = (half_t)acc[cc][r];
    }
    __syncthreads();
#pragma unroll
    for (int v = 0; v < 2; v++) {
        int idx = v * 256 + t; int r = idx >> 4, c8 = (idx & 15) * 8;
        *(half8*)&hA16[((size_t)(g + r) << 7) + c8] = *(const half8*)&htile[r * 136 + c8];
        *(half8*)&hbr16[((size_t)(g + r) << 7) + c8] = *(const half8*)&hbtile[r * 136 + c8];
    }
}

// ---------------- fused: em = masked(hA_i.hbr_j + hbr_i.hA_j); E2 = edge?exp(em-8):0 (f16);
//                  rs = 1/rowsum(exp(masked0 em - 8))   (row stats == col stats by symmetry)
__global__ __launch_bounds__(256)
void k_E(const half_t* __restrict__ hA16, const half_t* __restrict__ hbr16,
         const unsigned int* __restrict__ maskG, half_t* __restrict__ E2,
         float* __restrict__ rsb) {
    __shared__ half_t AjT[64 * 136];
    __shared__ half_t HjT[64 * 136];
    __shared__ unsigned int maskS[32 * 32];
    __shared__ half_t estage[32 * 72];
    __shared__ float sbuf[64];
    int b = blockIdx.y;
    int i0 = blockIdx.x * 32;
    int t = threadIdx.x;
    int w = t >> 6, l = t & 63, q = l >> 4, l15 = l & 15;
#pragma unroll
    for (int v = 0; v < 4; v++) {
        int idx = v * 256 + t;
        maskS[idx] = maskG[((size_t)(b * 1024 + i0)) * 32 + idx];
    }
    const half_t* Abase = hA16 + ((size_t)(b * 1024) << 7);
    const half_t* Hbase = hbr16 + ((size_t)(b * 1024) << 7);
#pragma unroll
    for (int v = 0; v < 2; v++) {
        int idx = v * 256 + t; int r = idx >> 4, c8 = (idx & 15) * 8;
        *(half8*)&AjT[r * 136 + c8] = *(const half8*)&Abase[((size_t)(i0 + r) << 7) + c8];
        *(half8*)&HjT[r * 136 + c8] = *(const half8*)&Hbase[((size_t)(i0 + r) << 7) + c8];
    }
    __syncthreads();
    int rowh = (w & 1) * 16;
    half8 Af[4], Hf[4];
#pragma unroll
    for (int kc = 0; kc < 4; kc++) {
        Af[kc] = *(const half8*)&AjT[(rowh + l15) * 136 + kc * 32 + q * 8];
        Hf[kc] = *(const half8*)&HjT[(rowh + l15) * 136 + kc * 32 + q * 8];
    }
    float ssum[4] = {0.f, 0.f, 0.f, 0.f};
    int c0 = (w >> 1) * 2;
    for (int jt = 0; jt < 16; jt++) {
        __syncthreads();   // frag reads + prior estage writeout done
#pragma unroll
        for (int v = 0; v < 4; v++) {
            int idx = v * 256 + t; int r = idx >> 4, c8 = (idx & 15) * 8;
            *(half8*)&AjT[r * 136 + c8] = *(const half8*)&Abase[((size_t)(jt * 64 + r) << 7) + c8];
            *(half8*)&HjT[r * 136 + c8] = *(const half8*)&Hbase[((size_t)(jt * 64 + r) << 7) + c8];
        }
        __syncthreads();
#pragma unroll
        for (int cc = 0; cc < 2; cc++) {
            int c = c0 + cc;
            floatx4 a = {0.f, 0.f, 0.f, 0.f};
#pragma unroll
            for (int kc = 0; kc < 4; kc++) {
                half8 bh = *(const half8*)&HjT[(c * 16 + l15) * 136 + kc * 32 + q * 8];
                a = MFMA(Af[kc], bh, a);
                half8 ba = *(const half8*)&AjT[(c * 16 + l15) * 136 + kc * 32 + q * 8];
                a = MFMA(Hf[kc], ba, a);
            }
            int colw = jt * 64 + c * 16 + l15;
            int wd = colw >> 5; int bit = colw & 31;
#pragma unroll
            for (int r = 0; r < 4; r++) {
                int rowl = rowh + q * 4 + r;
                unsigned int mword = maskS[rowl * 32 + wd];
                bool edge = (mword >> bit) & 1u;
                float v = edge ? a[r] : 0.f;
                float tv = __expf(v - 8.f);
                ssum[r] += tv;
                estage[rowl * 72 + c * 16 + l15] = edge ? (half_t)tv : (half_t)0.f;
            }
        }
        __syncthreads();
        {
            int r = t >> 3, c8 = (t & 7) * 8;
            *(half8*)&E2[((size_t)b << 20) + ((size_t)(i0 + r) << 10) + jt * 64 + c8]
                = *(const half8*)&estage[r * 72 + c8];
        }
    }
#pragma unroll
    for (int r = 0; r < 4; r++) {
        float s = ssum[r];
        s += __shfl_xor(s, 1); s += __shfl_xor(s, 2);
        s += __shfl_xor(s, 4); s += __shfl_xor(s, 8);
        ssum[r] = s;
    }
    if (l15 == 0) {
#pragma unroll
        for (int r = 0; r < 4; r++) sbuf[(w >> 1) * 32 + rowh + q * 4 + r] = ssum[r];
    }
    __syncthreads();
    if ((w >> 1) == 0 && l15 == 0) {
#pragma unroll
        for (int r = 0; r < 4; r++) {
            int rowl = rowh + q * 4 + r;
            rsb[b * 1024 + i0 + rowl] = 1.f / (sbuf[rowl] + sbuf[32 + rowl]);
        }
    }
}

// ---------------- z' staging: zT[b][d][n] = f16(rs[n] * z[n][d]); mode1 also z = c*h+(1-c)*az, write zf
__global__ __launch_bounds__(256)
void k_ztrans(const float* __restrict__ hbr, const float* __restrict__ az,
              const float* __restrict__ cfb, const float* __restrict__ rsb,
              float* __restrict__ zf, half_t* __restrict__ zT, int mode) {
    __shared__ half_t tile[128 * 72];
    int b = blockIdx.y, n0 = blockIdx.x * 64;
    int t = threadIdx.x;
#pragma unroll
    for (int v = 0; v < 8; v++) {
        int idx = v * 256 + t; int r = idx >> 5, c4 = (idx & 31) * 4;
        size_t gi = ((size_t)(b * 1024 + n0 + r) << 7) + c4;
        float4 hv = *(const float4*)&hbr[gi];
        float4 zv;
        if (mode == 1) {
            float4 av = *(const float4*)&az[gi];   // az already relu'd
            float cf = cfb[b * 1024 + n0 + r];
            zv.x = cf * hv.x + (1.f - cf) * av.x;
            zv.y = cf * hv.y + (1.f - cf) * av.y;
            zv.z = cf * hv.z + (1.f - cf) * av.z;
            zv.w = cf * hv.w + (1.f - cf) * av.w;
            *(float4*)&zf[gi] = zv;
        } else zv = hv;
        float rs = rsb[b * 1024 + n0 + r];
        tile[(c4 + 0) * 72 + r] = (half_t)(rs * zv.x);
        tile[(c4 + 1) * 72 + r] = (half_t)(rs * zv.y);
        tile[(c4 + 2) * 72 + r] = (half_t)(rs * zv.z);
        tile[(c4 + 3) * 72 + r] = (half_t)(rs * zv.w);
    }
    __syncthreads();
#pragma unroll
    for (int v = 0; v < 4; v++) {
        int idx = v * 256 + t; int d = idx >> 3, c8 = (idx & 7) * 8;
        *(half8*)&zT[((size_t)(b * 128 + d) << 10) + n0 + c8] = *(const half8*)&tile[d * 72 + c8];
    }
}

// ---------------- az = E2 @ z'  (f16 MFMA). mode0: outF=relu(az). mode1: z=c*h+(1-c)*relu(az),
//                  outF=z f32, zTout = f16 transposed rs-scaled
__global__ __launch_bounds__(256)
void k_az(const half_t* __restrict__ E2, const half_t* __restrict__ zTin,
          const float* __restrict__ hbr, const float* __restrict__ cfb,
          const float* __restrict__ rsb, float* __restrict__ outF,
          half_t* __restrict__ zTout, int mode) {
    __shared__ half_t Pt[32 * 72];
    __shared__ half_t Zt[128 * 72];
    int b = blockIdx.y, i0 = blockIdx.x * 32;
    int t = threadIdx.x;
    int w = t >> 6, l = t & 63, q = l >> 4, l15 = l & 15;
    int rowg = (w & 1) * 16, colh = (w >> 1) * 64;
    floatx4 acc[4] = {};
    for (int k0 = 0; k0 < 1024; k0 += 64) {
        {
            int r = t >> 3, c8 = (t & 7) * 8;
            *(half8*)&Pt[r * 72 + c8] =
                *(const half8*)&E2[((size_t)b << 20) + ((size_t)(i0 + r) << 10) + k0 + c8];
        }
#pragma unroll
        for (int v = 0; v < 4; v++) {
            int idx = v * 256 + t; int r = idx >> 3, c8 = (idx & 7) * 8;
            *(half8*)&Zt[r * 72 + c8] =
                *(const half8*)&zTin[((size_t)(b * 128 + r) << 10) + k0 + c8];
        }
        __syncthreads();
        half8 af0 = *(const half8*)&Pt[(rowg + l15) * 72 + q * 8];
        half8 af1 = *(const half8*)&Pt[(rowg + l15) * 72 + 32 + q * 8];
#pragma unroll
        for (int cc = 0; cc < 4; cc++) {
            half8 b0 = *(const half8*)&Zt[(colh + cc * 16 + l15) * 72 + q * 8];
            acc[cc] = MFMA(af0, b0, acc[cc]);
            half8 b1 = *(const half8*)&Zt[(colh + cc * 16 + l15) * 72 + 32 + q * 8];
            acc[cc] = MFMA(af1, b1, acc[cc]);
        }
        __syncthreads();
    }
    int nodeb = i0 + rowg + q * 4;
    if (mode == 0) {
#pragma unroll
        for (int cc = 0; cc < 4; cc++) {
            int col = colh + cc * 16 + l15;
#pragma unroll
            for (int r = 0; r < 4; r++)
                outF[((size_t)(b * 1024 + nodeb + r) << 7) + col] = fmaxf(acc[cc][r], 0.f);
        }
    } else {
        float4 cf4 = *(const float4*)&cfb[b * 1024 + nodeb];
        float4 rs4 = *(const float4*)&rsb[b * 1024 + nodeb];
        const float* cfp = &cf4.x; const float* rsp = &rs4.x;
#pragma unroll
        for (int cc = 0; cc < 4; cc++) {
            int col = colh + cc * 16 + l15;
            half4v zt;
#pragma unroll
            for (int r = 0; r < 4; r++) {
                float azv = fmaxf(acc[cc][r], 0.f);
                float hv = hbr[((size_t)(b * 1024 + nodeb + r) << 7) + col];
                float zv = cfp[r] * hv + (1.f - cfp[r]) * azv;
                outF[((size_t)(b * 1024 + nodeb + r) << 7) + col] = zv;
                zt[r] = (half_t)(rsp[r] * zv);
            }
            *(half4v*)&zTout[((size_t)(b * 128 + col) << 10) + nodeb] = zt;
        }
    }
}

// ---------------- gate coefficient: sigmoid([hbr, az] . gw + gb)
__global__ __launch_bounds__(256)
void k_coeff(const float* __restrict__ hbr, const float* __restrict__ az,
             const float* __restrict__ gw, const float* __restrict__ gb,
             float* __restrict__ cf) {
    int node = blockIdx.x * 4 + (threadIdx.x >> 6);
    int l = threadIdx.x & 63;
    const float* hp = hbr + (size_t)node * DD;
    const float* ap = az + (size_t)node * DD;
    float acc = hp[l] * gw[l] + hp[l + 64] * gw[l + 64] + ap[l] * gw[128 + l] + ap[l + 64] * gw[192 + l];
    for (int off = 32; off; off >>= 1) acc += __shfl_down(acc, off);
    if (l == 0) cf[node] = 1.f / (1.f + __expf(-(acc + gb[0])));
}

// ---------------- h = z2 - z1
__global__ __launch_bounds__(256)
void k_sub(const float* __restrict__ a2, const float* __restrict__ a1, float* __restrict__ o) {
    size_t i4 = ((size_t)blockIdx.x * 256 + threadIdx.x) * 4;
    float4 v2 = *(const float4*)&a2[i4];
    float4 v1 = *(const float4*)&a1[i4];
    float4 r;
    r.x = v2.x - v1.x; r.y = v2.y - v1.y; r.z = v2.z - v1.z; r.w = v2.w - v1.w;
    *(float4*)&o[i4] = r;
}

// ---------------- masked mean-pool + MLP head
__global__ __launch_bounds__(128)
void k_final(const float* __restrict__ h, const float* __restrict__ valid,
             const float* __restrict__ w0, const float* __restrict__ b0,
             const float* __restrict__ w1, const float* __restrict__ b1,
             const float* __restrict__ w2, const float* __restrict__ b2,
             const float* __restrict__ w3, const float* __restrict__ b3,
             float* __restrict__ out) {
    int b = blockIdx.x, t = threadIdx.x;
    __shared__ float y0[DD], y1[DD];
    __shared__ float sred[2];
    float vs = 0.f;
    for (int n = t; n < NLEN; n += 128) vs += valid[b * NLEN + n];
    for (int off = 32; off; off >>= 1) vs += __shfl_down(vs, off);
    if ((t & 63) == 0) sred[t >> 6] = vs;
    __syncthreads();
    float vsum = sred[0] + sred[1];
    const float* hb = h + (size_t)b * NLEN * DD;
    float acc = 0.f;
    for (int n = 0; n < NLEN; n++) acc += hb[(size_t)n * DD + t] * valid[b * NLEN + n];
    y0[t] = acc / vsum;
    __syncthreads();
    float a = b0[t];
    for (int k = 0; k < DD; k++) a += y0[k] * w0[t * DD + k];
    y1[t] = fmaxf(a, 0.f);
    __syncthreads();
    a = b1[t];
    for (int k = 0; k < DD; k++) a += y1[k] * w1[t * DD + k];
    y0[t] = fmaxf(a, 0.f);
    __syncthreads();
    a = b2[t];
    for (int k = 0; k < DD; k++) a += y0[k] * w2[t * DD + k];
    y1[t] = fmaxf(a, 0.f);
    __syncthreads();
    float p = y1[t] * w3[t];
    for (int off = 32; off; off >>= 1) p += __shfl_down(p, off);
    if ((t & 63) == 0) sred[t >> 6] = p;
    __syncthreads();
    if (t == 0) out[b] = 1.f / (1.f + __expf(-(sred[0] + sred[1] + b3[0])));
}

extern "C" void kernel_launch(void* const* d_in, const int* in_sizes, int n_in,
                              void* d_out, int out_size, void* d_ws, size_t ws_size,
                              hipStream_t stream) {
    (void)in_sizes; (void)n_in; (void)out_size; (void)ws_size;
    const float* x     = (const float*)d_in[0];
    const float* adj1  = (const float*)d_in[1];
    const float* adj2  = (const float*)d_in[2];
    const float* valid = (const float*)d_in[3];
    const float* Ew    = (const float*)d_in[4];
    const float* gW    = (const float*)d_in[5];
    const float* gb    = (const float*)d_in[6];
    const float* gA    = (const float*)d_in[7];
    const float* gatew = (const float*)d_in[8];
    const float* gateb = (const float*)d_in[9];
    const float* w0 = (const float*)d_in[10]; const float* b0 = (const float*)d_in[11];
    const float* w1 = (const float*)d_in[12]; const float* b1 = (const float*)d_in[13];
    const float* w2 = (const float*)d_in[14]; const float* b2 = (const float*)d_in[15];
    const float* w3 = (const float*)d_in[16]; const float* b3 = (const float*)d_in[17];
    float* out = (float*)d_out;

    // workspace carve (~92 MB)
    char* p = (char*)d_ws;
    float* h    = (float*)p; p += BND * 4;
    float* hbr  = (float*)p; p += BND * 4;
    float* az   = (float*)p; p += BND * 4;
    float* z1   = (float*)p; p += BND * 4;
    float* z2   = (float*)p; p += BND * 4;
    float* rsb  = (float*)p; p += BN * 4;
    float* cfb  = (float*)p; p += BN * 4;
    half_t* hbr16 = (half_t*)p; p += BND * 2;
    half_t* hA16  = (half_t*)p; p += BND * 2;
    half_t* E2    = (half_t*)p; p += BNN * 2;
    half_t* zT0   = (half_t*)p; p += BND * 2;
    half_t* zT1   = (half_t*)p; p += BND * 2;
    unsigned int* mask1 = (unsigned int*)p; p += (BNN / 32) * 4;
    unsigned int* mask2 = (unsigned int*)p; p += (BNN / 32) * 4;
    half_t* Wf16 = (half_t*)p; p += (size_t)4 * 128 * 128 * 2;
    half_t* AT16 = (half_t*)p; p += (size_t)4 * 128 * 128 * 2;

    k_wcast<<<256, 256, 0, stream>>>(gW, gA, Wf16, AT16);
    k_adjmask<<<2048, 256, 0, stream>>>(adj1, mask1);
    k_adjmask<<<2048, 256, 0, stream>>>(adj2, mask2);
    k_embed<<<2048, 256, 0, stream>>>(x, Ew, h);

    for (int k = 0; k < 4; k++) {
        int nhop = k + 1;
        for (int br = 0; br < 2; br++) {
            const unsigned int* msk = br ? mask2 : mask1;
            float* zf = br ? z2 : z1;
            k_proj<<<512, 256, 0, stream>>>(h, Wf16 + (size_t)k * 16384, gb + k * 128,
                                            AT16 + (size_t)k * 16384, hbr, hbr16, hA16);
            k_E<<<dim3(32, 16), 256, 0, stream>>>(hA16, hbr16, msk, E2, rsb);
            k_ztrans<<<dim3(16, 16), 256, 0, stream>>>(hbr, nullptr, nullptr, rsb, nullptr, zT0, 0);
            k_az<<<dim3(32, 16), 256, 0, stream>>>(E2, zT0, hbr, cfb, rsb, az, nullptr, 0);
            k_coeff<<<4096, 256, 0, stream>>>(hbr, az, gatew + k * 256, gateb + k, cfb);
            k_ztrans<<<dim3(16, 16), 256, 0, stream>>>(hbr, az, cfb, rsb, zf, zT1, 1);
            int cur = 1;
            for (int hop = 2; hop <= nhop; hop++) {
                k_az<<<dim3(32, 16), 256, 0, stream>>>(E2, cur ? zT1 : zT0, hbr, cfb, rsb,
                                                       zf, cur ? zT0 : zT1, 1);
                cur ^= 1;
            }
        }
        k_sub<<<2048, 256, 0, stream>>>(z2, z1, h);
    }
    k_final<<<16, 128, 0, stream>>>(h, valid, w0, b0, w1, b1, w2, b2, w3, b3, out);
}